// Round 1
// baseline (340.876 us; speedup 1.0000x reference)
//
#include <hip/hip_runtime.h>

#define B_ 8
#define C_ 256
#define C8_ 32
#define N_ 4096

typedef __bf16 bf16;
typedef __bf16 bf16x4 __attribute__((ext_vector_type(4)));
typedef __bf16 bf16x8 __attribute__((ext_vector_type(8)));
typedef float f32x4 __attribute__((ext_vector_type(4)));
typedef float f32x16 __attribute__((ext_vector_type(16)));

// ---------------- transpose + convert: x[b][c][n] f32 -> xT[b][n][c] bf16 ----
__global__ __launch_bounds__(256) void k_transpose(const float* __restrict__ x,
                                                   bf16* __restrict__ xT) {
  __shared__ bf16 t[64][72];   // 64c x 64n tile, padded
  int bid = blockIdx.x;
  int b = bid >> 8, rem = bid & 255;
  int c0 = (rem >> 6) * 64, n0 = (rem & 63) * 64;
  int tid = threadIdx.x;
#pragma unroll
  for (int r = 0; r < 4; ++r) {
    int cc = r * 16 + (tid >> 4);
    int j = (tid & 15) * 4;
    f32x4 v = *reinterpret_cast<const f32x4*>(
        x + ((size_t)b * C_ + c0 + cc) * N_ + n0 + j);
    bf16x4 o;
    o[0] = (bf16)v[0]; o[1] = (bf16)v[1]; o[2] = (bf16)v[2]; o[3] = (bf16)v[3];
    *reinterpret_cast<bf16x4*>(&t[cc][j]) = o;
  }
  __syncthreads();
#pragma unroll
  for (int r = 0; r < 2; ++r) {
    int nn = r * 32 + (tid >> 3);
    int c8 = (tid & 7) * 8;
    bf16x8 o;
#pragma unroll
    for (int k = 0; k < 8; ++k) o[k] = t[c8 + k][nn];
    *reinterpret_cast<bf16x8*>(
        xT + ((size_t)b * N_ + n0 + nn) * C_ + c0 + c8) = o;
  }
}

// ------------- Q/K projection: D[n][o] = sum_c x[c][n]*W[o][c] + b[o] --------
// store Qt/Kt as [b][n][32] bf16 (c-contiguous)
__global__ __launch_bounds__(256) void k_proj_qk(const bf16* __restrict__ xT,
    const float* __restrict__ wq, const float* __restrict__ bq,
    const float* __restrict__ wk, const float* __restrict__ bk,
    bf16* __restrict__ Qt, bf16* __restrict__ Kt) {
  int bid = blockIdx.x;
  int b = bid >> 5, nt = bid & 31;
  const float* W = blockIdx.y ? wk : wq;
  const float* bias = blockIdx.y ? bk : bq;
  bf16* Out = blockIdx.y ? Kt : Qt;
  int tid = threadIdx.x, lane = tid & 63, w = tid >> 6;
  int ln = lane & 31, h = lane >> 5;
  int n0 = nt * 128 + w * 32;
  const bf16* xp = xT + ((size_t)b * N_ + n0 + ln) * C_ + h * 8;
  const float* wp = W + (size_t)ln * C_ + h * 8;
  f32x16 acc;
#pragma unroll
  for (int r = 0; r < 16; ++r) acc[r] = 0.f;
#pragma unroll
  for (int ck = 0; ck < C_; ck += 16) {
    bf16x8 af = *reinterpret_cast<const bf16x8*>(xp + ck);  // A = x^T[n][c]
    f32x4 w0 = *reinterpret_cast<const f32x4*>(wp + ck);
    f32x4 w1 = *reinterpret_cast<const f32x4*>(wp + ck + 4);
    bf16x8 bfg;                                             // B = W^T[c][o]
    bfg[0] = (bf16)w0[0]; bfg[1] = (bf16)w0[1]; bfg[2] = (bf16)w0[2]; bfg[3] = (bf16)w0[3];
    bfg[4] = (bf16)w1[0]; bfg[5] = (bf16)w1[1]; bfg[6] = (bf16)w1[2]; bfg[7] = (bf16)w1[3];
    acc = __builtin_amdgcn_mfma_f32_32x32x16_bf16(af, bfg, acc, 0, 0, 0);
  }
  float bb = bias[ln];
#pragma unroll
  for (int r = 0; r < 16; ++r) {
    int n = n0 + (r & 3) + 8 * (r >> 2) + 4 * h;
    Out[((size_t)b * N_ + n) * C8_ + ln] = (bf16)(acc[r] + bb);
  }
}

// ------------- V projection: D[o][n] = sum_c W[o][c]*x[c][n] + b[o] ----------
// store V as [b][c][n] bf16 (n-contiguous)
__global__ __launch_bounds__(256) void k_proj_v(const bf16* __restrict__ xT,
    const float* __restrict__ wv, const float* __restrict__ bv,
    bf16* __restrict__ V) {
  int bid = blockIdx.x;
  int b = bid >> 8, rem = bid & 255;
  int ot = rem >> 5, nt = rem & 31;
  int tid = threadIdx.x, lane = tid & 63, w = tid >> 6;
  int ln = lane & 31, h = lane >> 5;
  int o0 = ot * 32;
  int n0 = nt * 128 + w * 32;
  const float* wp = wv + (size_t)(o0 + ln) * C_ + h * 8;
  const bf16* xp = xT + ((size_t)b * N_ + n0 + ln) * C_ + h * 8;
  f32x16 acc;
#pragma unroll
  for (int r = 0; r < 16; ++r) acc[r] = 0.f;
#pragma unroll
  for (int ck = 0; ck < C_; ck += 16) {
    f32x4 w0 = *reinterpret_cast<const f32x4*>(wp + ck);
    f32x4 w1 = *reinterpret_cast<const f32x4*>(wp + ck + 4);
    bf16x8 afg;                                             // A = W[o][c]
    afg[0] = (bf16)w0[0]; afg[1] = (bf16)w0[1]; afg[2] = (bf16)w0[2]; afg[3] = (bf16)w0[3];
    afg[4] = (bf16)w1[0]; afg[5] = (bf16)w1[1]; afg[6] = (bf16)w1[2]; afg[7] = (bf16)w1[3];
    bf16x8 bfg = *reinterpret_cast<const bf16x8*>(xp + ck); // B = x[c][n]
    acc = __builtin_amdgcn_mfma_f32_32x32x16_bf16(afg, bfg, acc, 0, 0, 0);
  }
#pragma unroll
  for (int r = 0; r < 16; ++r) {
    int c = o0 + (r & 3) + 8 * (r >> 2) + 4 * h;
    V[((size_t)b * C_ + c) * N_ + n0 + ln] = (bf16)(acc[r] + bv[c]);
  }
}

// ---------------- flash attention + residual --------------------------------
// block = (b, q-tile of 32). 4 waves. Per 128-m iter: wave w computes S^T for
// its 32-m slice (swapped mfma(K,Q): lane owns query column n=lane&31), online
// softmax combined across waves via LDS, P->bf16->LDS, PV: wave w owns 64
// channels, V A-frags straight from global (L2-resident per batch).
__global__ __launch_bounds__(256) void k_attn(const bf16* __restrict__ Qt,
    const bf16* __restrict__ Kt, const bf16* __restrict__ V,
    const float* __restrict__ x, float* __restrict__ out) {
  __shared__ float smax[4][32];
  __shared__ float ssum[4][32];
  __shared__ bf16 Pn[32][136];   // [n][m], m padded 128->136 (4-way max)
  int bid = blockIdx.x;
  int nb = (bid & 7) * 128 + (bid >> 3);   // bijective XCD swizzle: 1 batch/XCD
  int b = nb >> 7, qt = nb & 127;
  int n0 = qt * 32;
  int tid = threadIdx.x, lane = tid & 63, w = tid >> 6;
  int ln = lane & 31, h = lane >> 5;

  const bf16* qp = Qt + ((size_t)b * N_ + n0 + ln) * C8_ + h * 8;
  bf16x8 qf0 = *reinterpret_cast<const bf16x8*>(qp);        // B = Q[c][n]
  bf16x8 qf1 = *reinterpret_cast<const bf16x8*>(qp + 16);
  const bf16* Ktb = Kt + (size_t)b * N_ * C8_;
  const bf16* Vb = V + (size_t)b * C_ * N_;

  f32x16 o0, o1;
#pragma unroll
  for (int r = 0; r < 16; ++r) { o0[r] = 0.f; o1[r] = 0.f; }
  float M = -1e30f, L = 0.f;

  for (int m0 = 0; m0 < N_; m0 += 128) {
    // ---- S^T (32m x 32n) for this wave's m slice
    const bf16* kp = Ktb + (size_t)(m0 + w * 32 + ln) * C8_ + h * 8;
    bf16x8 kf0 = *reinterpret_cast<const bf16x8*>(kp);      // A = K^T[m][c]
    bf16x8 kf1 = *reinterpret_cast<const bf16x8*>(kp + 16);
    f32x16 s;
#pragma unroll
    for (int r = 0; r < 16; ++r) s[r] = 0.f;
    s = __builtin_amdgcn_mfma_f32_32x32x16_bf16(kf0, qf0, s, 0, 0, 0);
    s = __builtin_amdgcn_mfma_f32_32x32x16_bf16(kf1, qf1, s, 0, 0, 0);

    // ---- wave-local row max (per query column n = ln)
    float wm = s[0];
#pragma unroll
    for (int r = 1; r < 16; ++r) wm = fmaxf(wm, s[r]);
    wm = fmaxf(wm, __shfl_xor(wm, 32));
    if (lane < 32) smax[w][lane] = wm;
    __syncthreads();
    float im = fmaxf(fmaxf(smax[0][ln], smax[1][ln]),
                     fmaxf(smax[2][ln], smax[3][ln]));
    float newM = fmaxf(M, im);
    float scale = __expf(M - newM);

    float p[16];
    float ps = 0.f;
#pragma unroll
    for (int r = 0; r < 16; ++r) { p[r] = __expf(s[r] - newM); ps += p[r]; }
    ps += __shfl_xor(ps, 32);

    // ---- P -> bf16 -> LDS  (m_local = w*32 + (r&3) + 8*(r>>2) + 4h, n = ln)
#pragma unroll
    for (int g = 0; g < 4; ++g) {
      bf16x4 pk;
      pk[0] = (bf16)p[4 * g + 0]; pk[1] = (bf16)p[4 * g + 1];
      pk[2] = (bf16)p[4 * g + 2]; pk[3] = (bf16)p[4 * g + 3];
      *reinterpret_cast<bf16x4*>(&Pn[ln][w * 32 + g * 8 + h * 4]) = pk;
    }
    if (lane < 32) ssum[w][lane] = ps;
    __syncthreads();

    float is = ssum[0][ln] + ssum[1][ln] + ssum[2][ln] + ssum[3][ln];
    L = L * scale + is;
    M = newM;
#pragma unroll
    for (int r = 0; r < 16; ++r) { o0[r] *= scale; o1[r] *= scale; }

    // ---- PV: wave w owns channels [w*64, w*64+64)
    const bf16* vp0 = Vb + (size_t)(w * 64 + ln) * N_ + m0 + h * 8;
    const bf16* vp1 = vp0 + (size_t)32 * N_;
#pragma unroll
    for (int mk = 0; mk < 8; ++mk) {
      bf16x8 pf = *reinterpret_cast<const bf16x8*>(&Pn[ln][mk * 16 + h * 8]);
      bf16x8 vf0 = *reinterpret_cast<const bf16x8*>(vp0 + mk * 16);
      bf16x8 vf1 = *reinterpret_cast<const bf16x8*>(vp1 + mk * 16);
      o0 = __builtin_amdgcn_mfma_f32_32x32x16_bf16(vf0, pf, o0, 0, 0, 0);
      o1 = __builtin_amdgcn_mfma_f32_32x32x16_bf16(vf1, pf, o1, 0, 0, 0);
    }
    __syncthreads();
  }

  // ---- epilogue: out = O/L + x
  float invL = 1.f / L;
#pragma unroll
  for (int r = 0; r < 16; ++r) {
    int rr = (r & 3) + 8 * (r >> 2) + 4 * h;
    size_t i0 = ((size_t)b * C_ + w * 64 + rr) * N_ + n0 + ln;
    out[i0] = o0[r] * invL + x[i0];
    size_t i1 = i0 + (size_t)32 * N_;
    out[i1] = o1[r] * invL + x[i1];
  }
}

extern "C" void kernel_launch(void* const* d_in, const int* in_sizes, int n_in,
                              void* d_out, int out_size, void* d_ws, size_t ws_size,
                              hipStream_t stream) {
  const float* x  = (const float*)d_in[0];
  const float* wq = (const float*)d_in[1];
  const float* bq = (const float*)d_in[2];
  const float* wk = (const float*)d_in[3];
  const float* bk = (const float*)d_in[4];
  const float* wv = (const float*)d_in[5];
  const float* bv = (const float*)d_in[6];
  float* out = (float*)d_out;

  // ws layout (bf16): xT 16MB | Qt 2MB | Kt 2MB | V 16MB  = 36MB total
  bf16* xT = (bf16*)d_ws;
  bf16* Qt = xT + (size_t)B_ * N_ * C_;
  bf16* Kt = Qt + (size_t)B_ * N_ * C8_;
  bf16* Vv = Kt + (size_t)B_ * N_ * C8_;

  k_transpose<<<dim3(2048), dim3(256), 0, stream>>>(x, xT);
  k_proj_qk<<<dim3(256, 2), dim3(256), 0, stream>>>(xT, wq, bq, wk, bk, Qt, Kt);
  k_proj_v<<<dim3(2048), dim3(256), 0, stream>>>(xT, wv, bv, Vv);
  k_attn<<<dim3(1024), dim3(256), 0, stream>>>(Qt, Kt, Vv, x, out);
}

// Round 2
// 326.734 us; speedup vs baseline: 1.0433x; 1.0433x over previous
//
#include <hip/hip_runtime.h>

#define B_ 8
#define C_ 256
#define C8_ 32
#define N_ 4096

typedef __bf16 bf16;
typedef __bf16 bf16x4 __attribute__((ext_vector_type(4)));
typedef __bf16 bf16x8 __attribute__((ext_vector_type(8)));
typedef float f32x4 __attribute__((ext_vector_type(4)));
typedef float f32x16 __attribute__((ext_vector_type(16)));

#if __has_builtin(__builtin_amdgcn_exp2f)
#define EXP2 __builtin_amdgcn_exp2f
#else
#define EXP2 exp2f
#endif

#define CVTPK(lo, hi) ({ unsigned int _w;                                     \
  asm("v_cvt_pk_bf16_f32 %0, %1, %2" : "=v"(_w) : "v"(lo), "v"(hi)); _w; })
#define LSWAP(a, b) asm("v_permlane32_swap_b32 %0, %1" : "+v"(a), "+v"(b))

// ---------------- transpose + convert: x[b][c][n] f32 -> xT[b][n][c] bf16 ----
__global__ __launch_bounds__(256) void k_transpose(const float* __restrict__ x,
                                                   bf16* __restrict__ xT) {
  __shared__ bf16 t[64][72];
  int bid = blockIdx.x;
  int b = bid >> 8, rem = bid & 255;
  int c0 = (rem >> 6) * 64, n0 = (rem & 63) * 64;
  int tid = threadIdx.x;
#pragma unroll
  for (int r = 0; r < 4; ++r) {
    int cc = r * 16 + (tid >> 4);
    int j = (tid & 15) * 4;
    f32x4 v = *reinterpret_cast<const f32x4*>(
        x + ((size_t)b * C_ + c0 + cc) * N_ + n0 + j);
    bf16x4 o;
    o[0] = (bf16)v[0]; o[1] = (bf16)v[1]; o[2] = (bf16)v[2]; o[3] = (bf16)v[3];
    *reinterpret_cast<bf16x4*>(&t[cc][j]) = o;
  }
  __syncthreads();
#pragma unroll
  for (int r = 0; r < 2; ++r) {
    int nn = r * 32 + (tid >> 3);
    int c8 = (tid & 7) * 8;
    bf16x8 o;
#pragma unroll
    for (int k = 0; k < 8; ++k) o[k] = t[c8 + k][nn];
    *reinterpret_cast<bf16x8*>(
        xT + ((size_t)b * N_ + n0 + nn) * C_ + c0 + c8) = o;
  }
}

// ------------- Q/K projection (Q scaled by log2e) ---------------------------
__global__ __launch_bounds__(256) void k_proj_qk(const bf16* __restrict__ xT,
    const float* __restrict__ wq, const float* __restrict__ bq,
    const float* __restrict__ wk, const float* __restrict__ bk,
    bf16* __restrict__ Qt, bf16* __restrict__ Kt) {
  int bid = blockIdx.x;
  int b = bid >> 5, nt = bid & 31;
  const float* W = blockIdx.y ? wk : wq;
  const float* bias = blockIdx.y ? bk : bq;
  bf16* Out = blockIdx.y ? Kt : Qt;
  float scl = blockIdx.y ? 1.0f : 1.44269504f;   // fold log2e into Q
  int tid = threadIdx.x, lane = tid & 63, w = tid >> 6;
  int ln = lane & 31, h = lane >> 5;
  int n0 = nt * 128 + w * 32;
  const bf16* xp = xT + ((size_t)b * N_ + n0 + ln) * C_ + h * 8;
  const float* wp = W + (size_t)ln * C_ + h * 8;
  f32x16 acc;
#pragma unroll
  for (int r = 0; r < 16; ++r) acc[r] = 0.f;
#pragma unroll
  for (int ck = 0; ck < C_; ck += 16) {
    bf16x8 af = *reinterpret_cast<const bf16x8*>(xp + ck);
    f32x4 w0 = *reinterpret_cast<const f32x4*>(wp + ck);
    f32x4 w1 = *reinterpret_cast<const f32x4*>(wp + ck + 4);
    bf16x8 bfg;
    bfg[0] = (bf16)w0[0]; bfg[1] = (bf16)w0[1]; bfg[2] = (bf16)w0[2]; bfg[3] = (bf16)w0[3];
    bfg[4] = (bf16)w1[0]; bfg[5] = (bf16)w1[1]; bfg[6] = (bf16)w1[2]; bfg[7] = (bf16)w1[3];
    acc = __builtin_amdgcn_mfma_f32_32x32x16_bf16(af, bfg, acc, 0, 0, 0);
  }
  float bb = bias[ln];
#pragma unroll
  for (int r = 0; r < 16; ++r) {
    int n = n0 + (r & 3) + 8 * (r >> 2) + 4 * h;
    Out[((size_t)b * N_ + n) * C8_ + ln] = (bf16)((acc[r] + bb) * scl);
  }
}

// ------------- V projection: V[b][c][n] bf16 --------------------------------
__global__ __launch_bounds__(256) void k_proj_v(const bf16* __restrict__ xT,
    const float* __restrict__ wv, const float* __restrict__ bv,
    bf16* __restrict__ V) {
  int bid = blockIdx.x;
  int b = bid >> 8, rem = bid & 255;
  int ot = rem >> 5, nt = rem & 31;
  int tid = threadIdx.x, lane = tid & 63, w = tid >> 6;
  int ln = lane & 31, h = lane >> 5;
  int o0 = ot * 32;
  int n0 = nt * 128 + w * 32;
  const float* wp = wv + (size_t)(o0 + ln) * C_ + h * 8;
  const bf16* xp = xT + ((size_t)b * N_ + n0 + ln) * C_ + h * 8;
  f32x16 acc;
#pragma unroll
  for (int r = 0; r < 16; ++r) acc[r] = 0.f;
#pragma unroll
  for (int ck = 0; ck < C_; ck += 16) {
    f32x4 w0 = *reinterpret_cast<const f32x4*>(wp + ck);
    f32x4 w1 = *reinterpret_cast<const f32x4*>(wp + ck + 4);
    bf16x8 afg;
    afg[0] = (bf16)w0[0]; afg[1] = (bf16)w0[1]; afg[2] = (bf16)w0[2]; afg[3] = (bf16)w0[3];
    afg[4] = (bf16)w1[0]; afg[5] = (bf16)w1[1]; afg[6] = (bf16)w1[2]; afg[7] = (bf16)w1[3];
    bf16x8 bfg = *reinterpret_cast<const bf16x8*>(xp + ck);
    acc = __builtin_amdgcn_mfma_f32_32x32x16_bf16(afg, bfg, acc, 0, 0, 0);
  }
#pragma unroll
  for (int r = 0; r < 16; ++r) {
    int c = o0 + (r & 3) + 8 * (r >> 2) + 4 * h;
    V[((size_t)b * C_ + c) * N_ + n0 + ln] = (bf16)(acc[r] + bv[c]);
  }
}

// ---------------- flash attention, barrier-free main loop -------------------
// 512 blocks x 4 waves. Wave = (q-tile of 32, m-half of 2048), full C=256.
// Swapped QK^T: lane owns query column q=ln. In-register P via cvt_pk +
// permlane32_swap. Defer-max THR=8. Pair (half0, half1) merges via LDS at end.
__global__ __launch_bounds__(256, 2) void k_attn(const bf16* __restrict__ Qt,
    const bf16* __restrict__ Kt, const bf16* __restrict__ V,
    const float* __restrict__ x, float* __restrict__ out) {
  __shared__ float Ob[2][256][33];        // [pair][c][q] merge buffer
  __shared__ float sML[2][2][2][32];      // [pair][half][{M,L}][q]
  int bid = blockIdx.x;
  int b = bid & 7;                        // batch per XCD
  int task = bid >> 3;                    // 0..63
  int tid = threadIdx.x, lane = tid & 63, w = tid >> 6;
  int ln = lane & 31, h = lane >> 5;
  int pair = w >> 1, half = w & 1;
  int qt = task * 2 + pair;
  int n0 = qt * 32;

  const bf16* qp = Qt + ((size_t)b * N_ + n0 + ln) * C8_ + h * 8;
  bf16x8 qf0 = *reinterpret_cast<const bf16x8*>(qp);
  bf16x8 qf1 = *reinterpret_cast<const bf16x8*>(qp + 16);
  const bf16* Ktb = Kt + (size_t)b * N_ * C8_;
  const bf16* Vb = V + (size_t)b * C_ * N_;

  f32x16 o[8];
#pragma unroll
  for (int ct = 0; ct < 8; ++ct)
#pragma unroll
    for (int r = 0; r < 16; ++r) o[ct][r] = 0.f;
  float M = -1e30f, L = 0.f;

  const int mbase = half * 2048;
  for (int it = 0; it < 64; ++it) {
    int mm = mbase + it * 32;
    const bf16* kp = Ktb + (size_t)(mm + ln) * C8_ + h * 8;
    bf16x8 kf0 = *reinterpret_cast<const bf16x8*>(kp);
    bf16x8 kf1 = *reinterpret_cast<const bf16x8*>(kp + 16);
    f32x16 s;
#pragma unroll
    for (int r = 0; r < 16; ++r) s[r] = 0.f;
    s = __builtin_amdgcn_mfma_f32_32x32x16_bf16(kf0, qf0, s, 0, 0, 0);
    s = __builtin_amdgcn_mfma_f32_32x32x16_bf16(kf1, qf1, s, 0, 0, 0);

    // per-column (query) max over this 32-m tile, log2 domain
    float wm = fmaxf(fmaxf(fmaxf(s[0], s[1]), fmaxf(s[2], s[3])),
                     fmaxf(fmaxf(s[4], s[5]), fmaxf(s[6], s[7])));
    wm = fmaxf(wm, fmaxf(fmaxf(fmaxf(s[8], s[9]), fmaxf(s[10], s[11])),
                         fmaxf(fmaxf(s[12], s[13]), fmaxf(s[14], s[15]))));
    wm = fmaxf(wm, __shfl_xor(wm, 32));

    if (__any(wm > M + 8.f)) {           // defer-max rescale (T13)
      float Mn = fmaxf(M, wm);
      float sc = EXP2(M - Mn);
      L *= sc;
#pragma unroll
      for (int ct = 0; ct < 8; ++ct)
#pragma unroll
        for (int r = 0; r < 16; ++r) o[ct][r] *= sc;
      M = Mn;
    }

    float ps = 0.f;
#pragma unroll
    for (int r = 0; r < 16; ++r) { s[r] = EXP2(s[r] - M); ps += s[r]; }
    L += ps;

    // P f32 -> bf16 frags, in-register redistribution (T12)
    unsigned int c0 = CVTPK(s[0], s[1]),  c1 = CVTPK(s[2], s[3]);
    unsigned int c2 = CVTPK(s[4], s[5]),  c3 = CVTPK(s[6], s[7]);
    unsigned int c4 = CVTPK(s[8], s[9]),  c5 = CVTPK(s[10], s[11]);
    unsigned int c6 = CVTPK(s[12], s[13]), c7 = CVTPK(s[14], s[15]);
    LSWAP(c0, c2); LSWAP(c1, c3); LSWAP(c4, c6); LSWAP(c5, c7);
    union { unsigned int u[4]; bf16x8 v; } P0, P1;
    P0.u[0] = c0; P0.u[1] = c1; P0.u[2] = c2; P0.u[3] = c3;
    P1.u[0] = c4; P1.u[1] = c5; P1.u[2] = c6; P1.u[3] = c7;

    // PV over all 256 channels
    const bf16* vp = Vb + (size_t)ln * N_ + mm + h * 8;
#pragma unroll
    for (int ct = 0; ct < 8; ++ct) {
      bf16x8 vf0 = *reinterpret_cast<const bf16x8*>(vp + (size_t)ct * 32 * N_);
      bf16x8 vf1 = *reinterpret_cast<const bf16x8*>(vp + (size_t)ct * 32 * N_ + 16);
      o[ct] = __builtin_amdgcn_mfma_f32_32x32x16_bf16(vf0, P0.v, o[ct], 0, 0, 0);
      o[ct] = __builtin_amdgcn_mfma_f32_32x32x16_bf16(vf1, P1.v, o[ct], 0, 0, 0);
    }
  }

  // ---- pair merge (half0 + half1) via LDS ----
  L += __shfl_xor(L, 32);
  if (lane < 32) { sML[pair][half][0][lane] = M; sML[pair][half][1][lane] = L; }
  __syncthreads();
  float M0 = sML[pair][0][0][ln], L0 = sML[pair][0][1][ln];
  float M1 = sML[pair][1][0][ln], L1 = sML[pair][1][1][ln];
  float Ms = fmaxf(M0, M1);
  float a0 = EXP2(M0 - Ms), a1 = EXP2(M1 - Ms);
  float inv = 1.f / (L0 * a0 + L1 * a1);
  if (half) {
#pragma unroll
    for (int ct = 0; ct < 8; ++ct)
#pragma unroll
      for (int r = 0; r < 16; ++r) {
        int c = ct * 32 + (r & 3) + 8 * (r >> 2) + 4 * h;
        Ob[pair][c][ln] = o[ct][r] * a1;
      }
  }
  __syncthreads();
  if (!half) {
#pragma unroll
    for (int ct = 0; ct < 8; ++ct)
#pragma unroll
      for (int r = 0; r < 16; ++r) {
        int c = ct * 32 + (r & 3) + 8 * (r >> 2) + 4 * h;
        size_t idx = ((size_t)b * C_ + c) * N_ + n0 + ln;
        out[idx] = (o[ct][r] * a0 + Ob[pair][c][ln]) * inv + x[idx];
      }
  }
}

extern "C" void kernel_launch(void* const* d_in, const int* in_sizes, int n_in,
                              void* d_out, int out_size, void* d_ws, size_t ws_size,
                              hipStream_t stream) {
  const float* x  = (const float*)d_in[0];
  const float* wq = (const float*)d_in[1];
  const float* bq = (const float*)d_in[2];
  const float* wk = (const float*)d_in[3];
  const float* bk = (const float*)d_in[4];
  const float* wv = (const float*)d_in[5];
  const float* bv = (const float*)d_in[6];
  float* out = (float*)d_out;

  bf16* xT = (bf16*)d_ws;
  bf16* Qt = xT + (size_t)B_ * N_ * C_;
  bf16* Kt = Qt + (size_t)B_ * N_ * C8_;
  bf16* Vv = Kt + (size_t)B_ * N_ * C8_;

  k_transpose<<<dim3(2048), dim3(256), 0, stream>>>(x, xT);
  k_proj_qk<<<dim3(256, 2), dim3(256), 0, stream>>>(xT, wq, bq, wk, bk, Qt, Kt);
  k_proj_v<<<dim3(2048), dim3(256), 0, stream>>>(xT, wv, bv, Vv);
  k_attn<<<dim3(512), dim3(256), 0, stream>>>(Qt, Kt, Vv, x, out);
}

// Round 4
// 212.745 us; speedup vs baseline: 1.6023x; 1.5358x over previous
//
#include <hip/hip_runtime.h>

#define B_ 8
#define C_ 256
#define C8_ 32
#define N_ 4096

typedef __bf16 bf16;
typedef __bf16 bf16x4 __attribute__((ext_vector_type(4)));
typedef __bf16 bf16x8 __attribute__((ext_vector_type(8)));
typedef float f32x4 __attribute__((ext_vector_type(4)));
typedef float f32x16 __attribute__((ext_vector_type(16)));

#if __has_builtin(__builtin_amdgcn_exp2f)
#define EXP2 __builtin_amdgcn_exp2f
#else
#define EXP2 exp2f
#endif

#define CVTPK(lo, hi) ({ unsigned int _w;                                     \
  asm("v_cvt_pk_bf16_f32 %0, %1, %2" : "=v"(_w) : "v"(lo), "v"(hi)); _w; })
#define LSWAP(a, b) asm("v_permlane32_swap_b32 %0, %1" : "+v"(a), "+v"(b))

// ---------------- weights f32 -> bf16 (once) --------------------------------
// Wb layout: [0:8192) wq | [8192:16384) wk | [16384:81920) wv   (row-major [o][c])
__global__ __launch_bounds__(256) void k_convw(const float* __restrict__ wq,
    const float* __restrict__ wk, const float* __restrict__ wv,
    bf16* __restrict__ Wb) {
  int i = (blockIdx.x * 256 + threadIdx.x) * 4;
  const float* src; int off;
  if (i < 8192) { src = wq; off = i; }
  else if (i < 16384) { src = wk; off = i - 8192; }
  else { src = wv; off = i - 16384; }
  f32x4 v = *reinterpret_cast<const f32x4*>(src + off);
  bf16x4 o;
  o[0] = (bf16)v[0]; o[1] = (bf16)v[1]; o[2] = (bf16)v[2]; o[3] = (bf16)v[3];
  *reinterpret_cast<bf16x4*>(Wb + i) = o;
}

// ---------------- transpose + convert: x[b][c][n] f32 -> xT[b][n][c] bf16 ----
__global__ __launch_bounds__(256) void k_transpose(const float* __restrict__ x,
                                                   bf16* __restrict__ xT) {
  __shared__ bf16 t[64][72];
  int bid = blockIdx.x;
  int b = bid >> 8, rem = bid & 255;
  int c0 = (rem >> 6) * 64, n0 = (rem & 63) * 64;
  int tid = threadIdx.x;
#pragma unroll
  for (int r = 0; r < 4; ++r) {
    int cc = r * 16 + (tid >> 4);
    int j = (tid & 15) * 4;
    f32x4 v = *reinterpret_cast<const f32x4*>(
        x + ((size_t)b * C_ + c0 + cc) * N_ + n0 + j);
    bf16x4 o;
    o[0] = (bf16)v[0]; o[1] = (bf16)v[1]; o[2] = (bf16)v[2]; o[3] = (bf16)v[3];
    *reinterpret_cast<bf16x4*>(&t[cc][j]) = o;
  }
  __syncthreads();
#pragma unroll
  for (int r = 0; r < 2; ++r) {
    int nn = r * 32 + (tid >> 3);
    int c8 = (tid & 7) * 8;
    bf16x8 o;
#pragma unroll
    for (int k = 0; k < 8; ++k) o[k] = t[c8 + k][nn];
    *reinterpret_cast<bf16x8*>(
        xT + ((size_t)b * N_ + n0 + nn) * C_ + c0 + c8) = o;
  }
}

// ------------- Q/K projection (Q scaled by log2e), bf16 weights -------------
__global__ __launch_bounds__(256) void k_proj_qk(const bf16* __restrict__ xT,
    const bf16* __restrict__ Wb,
    const float* __restrict__ bq, const float* __restrict__ bk,
    bf16* __restrict__ Qt, bf16* __restrict__ Kt) {
  int bid = blockIdx.x;
  int b = bid >> 5, nt = bid & 31;
  const bf16* W = Wb + (blockIdx.y ? 8192 : 0);
  const float* bias = blockIdx.y ? bk : bq;
  bf16* Out = blockIdx.y ? Kt : Qt;
  float scl = blockIdx.y ? 1.0f : 1.44269504f;
  int tid = threadIdx.x, lane = tid & 63, w = tid >> 6;
  int ln = lane & 31, h = lane >> 5;
  int n0 = nt * 128 + w * 32;
  const bf16* xp = xT + ((size_t)b * N_ + n0 + ln) * C_ + h * 8;
  const bf16* wp = W + (size_t)ln * C_ + h * 8;
  f32x16 acc;
#pragma unroll
  for (int r = 0; r < 16; ++r) acc[r] = 0.f;
#pragma unroll
  for (int ck = 0; ck < C_; ck += 16) {
    bf16x8 af = *reinterpret_cast<const bf16x8*>(xp + ck);
    bf16x8 bfg = *reinterpret_cast<const bf16x8*>(wp + ck);
    acc = __builtin_amdgcn_mfma_f32_32x32x16_bf16(af, bfg, acc, 0, 0, 0);
  }
  float bb = bias[ln];
#pragma unroll
  for (int r = 0; r < 16; ++r) {
    int n = n0 + (r & 3) + 8 * (r >> 2) + 4 * h;
    Out[((size_t)b * N_ + n) * C8_ + ln] = (bf16)((acc[r] + bb) * scl);
  }
}

// ------------- V projection -> TILED layout Vt[b][m/32][c][m%32] bf16 -------
__global__ __launch_bounds__(256) void k_proj_v(const bf16* __restrict__ xT,
    const bf16* __restrict__ Wb, const float* __restrict__ bv,
    bf16* __restrict__ Vt) {
  int bid = blockIdx.x;
  int b = bid >> 8, rem = bid & 255;
  int ot = rem >> 5, nt = rem & 31;
  int tid = threadIdx.x, lane = tid & 63, w = tid >> 6;
  int ln = lane & 31, h = lane >> 5;
  int o0 = ot * 32;
  int n0 = nt * 128 + w * 32;
  const bf16* wp = Wb + 16384 + (size_t)(o0 + ln) * C_ + h * 8;
  const bf16* xp = xT + ((size_t)b * N_ + n0 + ln) * C_ + h * 8;
  f32x16 acc;
#pragma unroll
  for (int r = 0; r < 16; ++r) acc[r] = 0.f;
#pragma unroll
  for (int ck = 0; ck < C_; ck += 16) {
    bf16x8 afg = *reinterpret_cast<const bf16x8*>(wp + ck);
    bf16x8 bfg = *reinterpret_cast<const bf16x8*>(xp + ck);
    acc = __builtin_amdgcn_mfma_f32_32x32x16_bf16(afg, bfg, acc, 0, 0, 0);
  }
  int mt = n0 >> 5;   // m-tile index
  // FIX(R3): tile stride is 256c*32m = 8192 elements (was *256 -> overlap)
  bf16* base = Vt + (size_t)(b * 128 + mt) * 256 * 32;
#pragma unroll
  for (int r = 0; r < 16; ++r) {
    int c = o0 + (r & 3) + 8 * (r >> 2) + 4 * h;
    base[(size_t)c * 32 + ln] = (bf16)(acc[r] + bv[c]);
  }
}

// ---------------- flash attention ------------------------------------------
// 1024 blocks x 4 waves. Block = (b, q-tile of 32). Wave w: ch = w>>1 owns
// 128 channels, mh = w&1 owns an m-half (2048). QK^T duplicated across ch pair
// (M/L bitwise-identical). Dense tiled V reads. End merge: mh=1 dumps rescaled
// O to LDS, mh=0 adds + writes out.
__global__ __launch_bounds__(256, 3) void k_attn(const bf16* __restrict__ Qt,
    const bf16* __restrict__ Kt, const bf16* __restrict__ Vt,
    const float* __restrict__ x, float* __restrict__ out) {
  __shared__ float Ob[2][128][33];     // [ch][c_local][q]
  __shared__ float sML[2][2][32];      // [mh][{M,L}][q]
  int bid = blockIdx.x;
  int b = bid & 7;                     // batch == XCD
  int qt = bid >> 3;                   // 0..127
  int n0 = qt * 32;
  int tid = threadIdx.x, lane = tid & 63, w = tid >> 6;
  int ln = lane & 31, h = lane >> 5;
  int ch = w >> 1, mh = w & 1;

  const bf16* qp = Qt + ((size_t)b * N_ + n0 + ln) * C8_ + h * 8;
  bf16x8 qf0 = *reinterpret_cast<const bf16x8*>(qp);
  bf16x8 qf1 = *reinterpret_cast<const bf16x8*>(qp + 16);
  const bf16* Ktb = Kt + (size_t)b * N_ * C8_;
  const bf16* Vtb = Vt + ((size_t)b * 128 + mh * 64) * 256 * 32
                       + ((size_t)ch * 128 + ln) * 32 + h * 8;

  f32x16 o[4];
#pragma unroll
  for (int ct = 0; ct < 4; ++ct)
#pragma unroll
    for (int r = 0; r < 16; ++r) o[ct][r] = 0.f;
  float M = -1e30f, L = 0.f;

  const bf16* kp = Ktb + (size_t)(mh * 2048 + ln) * C8_ + h * 8;
  for (int it = 0; it < 64; ++it) {
    bf16x8 kf0 = *reinterpret_cast<const bf16x8*>(kp);
    bf16x8 kf1 = *reinterpret_cast<const bf16x8*>(kp + 16);
    f32x16 s;
#pragma unroll
    for (int r = 0; r < 16; ++r) s[r] = 0.f;
    s = __builtin_amdgcn_mfma_f32_32x32x16_bf16(kf0, qf0, s, 0, 0, 0);
    s = __builtin_amdgcn_mfma_f32_32x32x16_bf16(kf1, qf1, s, 0, 0, 0);

    float wm = fmaxf(fmaxf(fmaxf(s[0], s[1]), fmaxf(s[2], s[3])),
                     fmaxf(fmaxf(s[4], s[5]), fmaxf(s[6], s[7])));
    wm = fmaxf(wm, fmaxf(fmaxf(fmaxf(s[8], s[9]), fmaxf(s[10], s[11])),
                         fmaxf(fmaxf(s[12], s[13]), fmaxf(s[14], s[15]))));
    wm = fmaxf(wm, __shfl_xor(wm, 32));

    if (__any(wm > M + 8.f)) {          // defer-max (T13)
      float Mn = fmaxf(M, wm);
      float sc = EXP2(M - Mn);
      L *= sc;
#pragma unroll
      for (int ct = 0; ct < 4; ++ct)
#pragma unroll
        for (int r = 0; r < 16; ++r) o[ct][r] *= sc;
      M = Mn;
    }

    float ps = 0.f;
#pragma unroll
    for (int r = 0; r < 16; ++r) { s[r] = EXP2(s[r] - M); ps += s[r]; }
    L += ps;

    // P f32 -> bf16 frags in-register (T12)
    unsigned int c0 = CVTPK(s[0], s[1]),  c1 = CVTPK(s[2], s[3]);
    unsigned int c2 = CVTPK(s[4], s[5]),  c3 = CVTPK(s[6], s[7]);
    unsigned int c4 = CVTPK(s[8], s[9]),  c5 = CVTPK(s[10], s[11]);
    unsigned int c6 = CVTPK(s[12], s[13]), c7 = CVTPK(s[14], s[15]);
    LSWAP(c0, c2); LSWAP(c1, c3); LSWAP(c4, c6); LSWAP(c5, c7);
    union { unsigned int u[4]; bf16x8 v; } P0, P1;
    P0.u[0] = c0; P0.u[1] = c1; P0.u[2] = c2; P0.u[3] = c3;
    P1.u[0] = c4; P1.u[1] = c5; P1.u[2] = c6; P1.u[3] = c7;

    // PV: dense tiled V reads, 2KB spans
    const bf16* vp = Vtb + (size_t)it * 256 * 32;
#pragma unroll
    for (int ct = 0; ct < 4; ++ct) {
      bf16x8 vf0 = *reinterpret_cast<const bf16x8*>(vp + ct * 1024);
      bf16x8 vf1 = *reinterpret_cast<const bf16x8*>(vp + ct * 1024 + 16);
      o[ct] = __builtin_amdgcn_mfma_f32_32x32x16_bf16(vf0, P0.v, o[ct], 0, 0, 0);
      o[ct] = __builtin_amdgcn_mfma_f32_32x32x16_bf16(vf1, P1.v, o[ct], 0, 0, 0);
    }
    kp += 32 * C8_;
  }

  // ---- merge the two m-halves ----
  L += __shfl_xor(L, 32);
  if (lane < 32) { sML[mh][0][lane] = M; sML[mh][1][lane] = L; }
  __syncthreads();
  float M0 = sML[0][0][ln], L0 = sML[0][1][ln];
  float M1 = sML[1][0][ln], L1 = sML[1][1][ln];
  float Ms = fmaxf(M0, M1);
  float a0 = EXP2(M0 - Ms), a1 = EXP2(M1 - Ms);
  float inv = 1.f / (L0 * a0 + L1 * a1);
  if (mh) {
#pragma unroll
    for (int ct = 0; ct < 4; ++ct)
#pragma unroll
      for (int r = 0; r < 16; ++r) {
        int cl = ct * 32 + (r & 3) + 8 * (r >> 2) + 4 * h;
        Ob[ch][cl][ln] = o[ct][r] * a1;
      }
  }
  __syncthreads();
  if (!mh) {
#pragma unroll
    for (int ct = 0; ct < 4; ++ct)
#pragma unroll
      for (int r = 0; r < 16; ++r) {
        int cl = ct * 32 + (r & 3) + 8 * (r >> 2) + 4 * h;
        size_t idx = ((size_t)b * C_ + ch * 128 + cl) * N_ + n0 + ln;
        out[idx] = (o[ct][r] * a0 + Ob[ch][cl][ln]) * inv + x[idx];
      }
  }
}

extern "C" void kernel_launch(void* const* d_in, const int* in_sizes, int n_in,
                              void* d_out, int out_size, void* d_ws, size_t ws_size,
                              hipStream_t stream) {
  const float* x  = (const float*)d_in[0];
  const float* wq = (const float*)d_in[1];
  const float* bq = (const float*)d_in[2];
  const float* wk = (const float*)d_in[3];
  const float* bk = (const float*)d_in[4];
  const float* wv = (const float*)d_in[5];
  const float* bv = (const float*)d_in[6];
  float* out = (float*)d_out;

  // ws (bf16 elems): xT 8M | Qt 1M | Kt 1M | Vt 8M | Wb 80K
  bf16* xT = (bf16*)d_ws;
  bf16* Qt = xT + (size_t)B_ * N_ * C_;
  bf16* Kt = Qt + (size_t)B_ * N_ * C8_;
  bf16* Vt = Kt + (size_t)B_ * N_ * C8_;
  bf16* Wb = Vt + (size_t)B_ * N_ * C_;

  k_convw<<<dim3(80), dim3(256), 0, stream>>>(wq, wk, wv, Wb);
  k_transpose<<<dim3(2048), dim3(256), 0, stream>>>(x, xT);
  k_proj_qk<<<dim3(256, 2), dim3(256), 0, stream>>>(xT, Wb, bq, bk, Qt, Kt);
  k_proj_v<<<dim3(2048), dim3(256), 0, stream>>>(xT, Wb, bv, Vt);
  k_attn<<<dim3(1024), dim3(256), 0, stream>>>(Qt, Kt, Vt, x, out);
}

// Round 5
// 210.543 us; speedup vs baseline: 1.6190x; 1.0105x over previous
//
#include <hip/hip_runtime.h>

#define B_ 8
#define C_ 256
#define C8_ 32
#define N_ 4096

typedef __bf16 bf16;
typedef __bf16 bf16x4 __attribute__((ext_vector_type(4)));
typedef __bf16 bf16x8 __attribute__((ext_vector_type(8)));
typedef float f32x4 __attribute__((ext_vector_type(4)));
typedef float f32x16 __attribute__((ext_vector_type(16)));

#if __has_builtin(__builtin_amdgcn_exp2f)
#define EXP2 __builtin_amdgcn_exp2f
#else
#define EXP2 exp2f
#endif

#define CVTPK(lo, hi) ({ unsigned int _w;                                     \
  asm("v_cvt_pk_bf16_f32 %0, %1, %2" : "=v"(_w) : "v"(lo), "v"(hi)); _w; })
#define LSWAP(a, b) asm("v_permlane32_swap_b32 %0, %1" : "+v"(a), "+v"(b))

// ---------------- weights f32 -> bf16 (once) --------------------------------
__global__ __launch_bounds__(256) void k_convw(const float* __restrict__ wq,
    const float* __restrict__ wk, const float* __restrict__ wv,
    bf16* __restrict__ Wb) {
  int i = (blockIdx.x * 256 + threadIdx.x) * 4;
  const float* src; int off;
  if (i < 8192) { src = wq; off = i; }
  else if (i < 16384) { src = wk; off = i - 8192; }
  else { src = wv; off = i - 16384; }
  f32x4 v = *reinterpret_cast<const f32x4*>(src + off);
  bf16x4 o;
  o[0] = (bf16)v[0]; o[1] = (bf16)v[1]; o[2] = (bf16)v[2]; o[3] = (bf16)v[3];
  *reinterpret_cast<bf16x4*>(Wb + i) = o;
}

// ---------------- transpose + convert: x[b][c][n] f32 -> xT[b][n][c] bf16 ----
// XCD swizzle: batch b runs on XCD b -> warms XCD-local L2 with xT[b]
__global__ __launch_bounds__(256) void k_transpose(const float* __restrict__ x,
                                                   bf16* __restrict__ xT) {
  __shared__ bf16 t[64][72];
  int bid = blockIdx.x;
  int b = bid & 7, rem = bid >> 3;
  int c0 = (rem >> 6) * 64, n0 = (rem & 63) * 64;
  int tid = threadIdx.x;
#pragma unroll
  for (int r = 0; r < 4; ++r) {
    int cc = r * 16 + (tid >> 4);
    int j = (tid & 15) * 4;
    f32x4 v = *reinterpret_cast<const f32x4*>(
        x + ((size_t)b * C_ + c0 + cc) * N_ + n0 + j);
    bf16x4 o;
    o[0] = (bf16)v[0]; o[1] = (bf16)v[1]; o[2] = (bf16)v[2]; o[3] = (bf16)v[3];
    *reinterpret_cast<bf16x4*>(&t[cc][j]) = o;
  }
  __syncthreads();
#pragma unroll
  for (int r = 0; r < 2; ++r) {
    int nn = r * 32 + (tid >> 3);
    int c8 = (tid & 7) * 8;
    bf16x8 o;
#pragma unroll
    for (int k = 0; k < 8; ++k) o[k] = t[c8 + k][nn];
    *reinterpret_cast<bf16x8*>(
        xT + ((size_t)b * N_ + n0 + nn) * C_ + c0 + c8) = o;
  }
}

// ------------- Q/K projection (Q scaled by log2e), bf16 weights -------------
__global__ __launch_bounds__(256) void k_proj_qk(const bf16* __restrict__ xT,
    const bf16* __restrict__ Wb,
    const float* __restrict__ bq, const float* __restrict__ bk,
    bf16* __restrict__ Qt, bf16* __restrict__ Kt) {
  int bid = blockIdx.x;
  int b = bid & 7, nt = bid >> 3;          // XCD swizzle: batch == XCD
  const bf16* W = Wb + (blockIdx.y ? 8192 : 0);
  const float* bias = blockIdx.y ? bk : bq;
  bf16* Out = blockIdx.y ? Kt : Qt;
  float scl = blockIdx.y ? 1.0f : 1.44269504f;
  int tid = threadIdx.x, lane = tid & 63, w = tid >> 6;
  int ln = lane & 31, h = lane >> 5;
  int n0 = nt * 128 + w * 32;
  const bf16* xp = xT + ((size_t)b * N_ + n0 + ln) * C_ + h * 8;
  const bf16* wp = W + (size_t)ln * C_ + h * 8;
  f32x16 acc;
#pragma unroll
  for (int r = 0; r < 16; ++r) acc[r] = 0.f;
#pragma unroll
  for (int ck = 0; ck < C_; ck += 16) {
    bf16x8 af = *reinterpret_cast<const bf16x8*>(xp + ck);
    bf16x8 bfg = *reinterpret_cast<const bf16x8*>(wp + ck);
    acc = __builtin_amdgcn_mfma_f32_32x32x16_bf16(af, bfg, acc, 0, 0, 0);
  }
  float bb = bias[ln];
#pragma unroll
  for (int r = 0; r < 16; ++r) {
    int n = n0 + (r & 3) + 8 * (r >> 2) + 4 * h;
    Out[((size_t)b * N_ + n) * C8_ + ln] = (bf16)((acc[r] + bb) * scl);
  }
}

// ------------- V projection -> TILED layout Vt[b][m/32][c][m%32] bf16 -------
__global__ __launch_bounds__(256) void k_proj_v(const bf16* __restrict__ xT,
    const bf16* __restrict__ Wb, const float* __restrict__ bv,
    bf16* __restrict__ Vt) {
  int bid = blockIdx.x;
  int b = bid & 7, rem = bid >> 3;         // XCD swizzle: xT[b] L2-resident
  int ot = rem >> 5, nt = rem & 31;
  int tid = threadIdx.x, lane = tid & 63, w = tid >> 6;
  int ln = lane & 31, h = lane >> 5;
  int o0 = ot * 32;
  int n0 = nt * 128 + w * 32;
  const bf16* wp = Wb + 16384 + (size_t)(o0 + ln) * C_ + h * 8;
  const bf16* xp = xT + ((size_t)b * N_ + n0 + ln) * C_ + h * 8;
  f32x16 acc;
#pragma unroll
  for (int r = 0; r < 16; ++r) acc[r] = 0.f;
#pragma unroll
  for (int ck = 0; ck < C_; ck += 16) {
    bf16x8 afg = *reinterpret_cast<const bf16x8*>(wp + ck);
    bf16x8 bfg = *reinterpret_cast<const bf16x8*>(xp + ck);
    acc = __builtin_amdgcn_mfma_f32_32x32x16_bf16(afg, bfg, acc, 0, 0, 0);
  }
  int mt = n0 >> 5;
  bf16* base = Vt + (size_t)(b * 128 + mt) * 256 * 32;
#pragma unroll
  for (int r = 0; r < 16; ++r) {
    int c = o0 + (r & 3) + 8 * (r >> 2) + 4 * h;
    base[(size_t)c * 32 + ln] = (bf16)(acc[r] + bv[c]);
  }
}

// ---------------- flash attention, 2-stage software pipeline ----------------
// 1024 blocks x 4 waves; wave = (ch: 128 channels, mh: m-half). Body(t):
// prefetch V(t+1)/K(t+2) to regs, QK+softmax for tile t+1 (VALU) interleaved
// with PV(t) (MFMA); o-rescale deferred to after PV. 2 waves/SIMD.
__global__ __launch_bounds__(256, 2) void k_attn(const bf16* __restrict__ Qt,
    const bf16* __restrict__ Kt, const bf16* __restrict__ Vt,
    const float* __restrict__ x, float* __restrict__ out) {
  __shared__ float Ob[2][128][33];
  __shared__ float sML[2][2][32];
  int bid = blockIdx.x;
  int b = bid & 7;
  int qt = bid >> 3;
  int n0 = qt * 32;
  int tid = threadIdx.x, lane = tid & 63, w = tid >> 6;
  int ln = lane & 31, h = lane >> 5;
  int ch = w >> 1, mh = w & 1;

  const bf16* qp = Qt + ((size_t)b * N_ + n0 + ln) * C8_ + h * 8;
  bf16x8 qf0 = *reinterpret_cast<const bf16x8*>(qp);
  bf16x8 qf1 = *reinterpret_cast<const bf16x8*>(qp + 16);
  const bf16* Kbase = Kt + (size_t)b * N_ * C8_
                         + ((size_t)(mh * 2048) + ln) * C8_ + h * 8;
  const bf16* Vbase = Vt + ((size_t)b * 128 + mh * 64) * 8192
                         + ((size_t)ch * 128 + ln) * 32 + h * 8;

  f32x16 o[4];
#pragma unroll
  for (int ct = 0; ct < 4; ++ct)
#pragma unroll
    for (int r = 0; r < 16; ++r) o[ct][r] = 0.f;

  bf16x8 kf[2][2], vf[2][8];
  union Pu { unsigned int u[4]; bf16x8 v; } P0[2], P1[2];
  float M, L;

  // ---- prologue: K(0),K(1),V(0); S(0); softmax(0) ----
  kf[0][0] = *reinterpret_cast<const bf16x8*>(Kbase);
  kf[0][1] = *reinterpret_cast<const bf16x8*>(Kbase + 16);
  kf[1][0] = *reinterpret_cast<const bf16x8*>(Kbase + 1024);
  kf[1][1] = *reinterpret_cast<const bf16x8*>(Kbase + 1024 + 16);
#pragma unroll
  for (int j = 0; j < 8; ++j)
    vf[0][j] = *reinterpret_cast<const bf16x8*>(
        Vbase + (j >> 1) * 1024 + (j & 1) * 16);
  {
    f32x16 s;
#pragma unroll
    for (int r = 0; r < 16; ++r) s[r] = 0.f;
    s = __builtin_amdgcn_mfma_f32_32x32x16_bf16(kf[0][0], qf0, s, 0, 0, 0);
    s = __builtin_amdgcn_mfma_f32_32x32x16_bf16(kf[0][1], qf1, s, 0, 0, 0);
    float m0 = fmaxf(fmaxf(fmaxf(s[0], s[1]), fmaxf(s[2], s[3])),
                     fmaxf(fmaxf(s[4], s[5]), fmaxf(s[6], s[7])));
    float m1 = fmaxf(fmaxf(fmaxf(s[8], s[9]), fmaxf(s[10], s[11])),
                     fmaxf(fmaxf(s[12], s[13]), fmaxf(s[14], s[15])));
    float wm = fmaxf(m0, m1);
    wm = fmaxf(wm, __shfl_xor(wm, 32));
    M = wm;
#pragma unroll
    for (int r = 0; r < 16; ++r) s[r] = EXP2(s[r] - M);
    float q0 = (s[0] + s[1]) + (s[2] + s[3]);
    float q1 = (s[4] + s[5]) + (s[6] + s[7]);
    float q2 = (s[8] + s[9]) + (s[10] + s[11]);
    float q3 = (s[12] + s[13]) + (s[14] + s[15]);
    L = (q0 + q1) + (q2 + q3);
    unsigned int c0 = CVTPK(s[0], s[1]),   c1 = CVTPK(s[2], s[3]);
    unsigned int c2 = CVTPK(s[4], s[5]),   c3 = CVTPK(s[6], s[7]);
    unsigned int c4 = CVTPK(s[8], s[9]),   c5 = CVTPK(s[10], s[11]);
    unsigned int c6 = CVTPK(s[12], s[13]), c7 = CVTPK(s[14], s[15]);
    LSWAP(c0, c2); LSWAP(c1, c3); LSWAP(c4, c6); LSWAP(c5, c7);
    P0[0].u[0] = c0; P0[0].u[1] = c1; P0[0].u[2] = c2; P0[0].u[3] = c3;
    P1[0].u[0] = c4; P1[0].u[1] = c5; P1[0].u[2] = c6; P1[0].u[3] = c7;
  }

  // ---- main loop ----
#pragma unroll 2
  for (int t = 0; t < 64; ++t) {
    int cur = t & 1, nxt = cur ^ 1;
    int tv = (t + 1 > 63) ? 63 : t + 1;
    int tk = (t + 2 > 63) ? 63 : t + 2;
    // prefetch V(t+1), K(t+2)
#pragma unroll
    for (int j = 0; j < 8; ++j)
      vf[nxt][j] = *reinterpret_cast<const bf16x8*>(
          Vbase + (size_t)tv * 8192 + (j >> 1) * 1024 + (j & 1) * 16);
    kf[cur][0] = *reinterpret_cast<const bf16x8*>(Kbase + (size_t)tk * 1024);
    kf[cur][1] = *reinterpret_cast<const bf16x8*>(Kbase + (size_t)tk * 1024 + 16);

    // S(t+1) from kf[nxt] (loaded two bodies ago)
    f32x16 s;
#pragma unroll
    for (int r = 0; r < 16; ++r) s[r] = 0.f;
    s = __builtin_amdgcn_mfma_f32_32x32x16_bf16(kf[nxt][0], qf0, s, 0, 0, 0);
    s = __builtin_amdgcn_mfma_f32_32x32x16_bf16(kf[nxt][1], qf1, s, 0, 0, 0);

    // softmax(t+1) — independent of PV(t) below; compiler interleaves
    float m0 = fmaxf(fmaxf(fmaxf(s[0], s[1]), fmaxf(s[2], s[3])),
                     fmaxf(fmaxf(s[4], s[5]), fmaxf(s[6], s[7])));
    float m1 = fmaxf(fmaxf(fmaxf(s[8], s[9]), fmaxf(s[10], s[11])),
                     fmaxf(fmaxf(s[12], s[13]), fmaxf(s[14], s[15])));
    float wm = fmaxf(m0, m1);
    wm = fmaxf(wm, __shfl_xor(wm, 32));
    bool commit = t < 63;
    bool resc = commit && __any(wm > M + 8.f);
    float Mn = resc ? fmaxf(M, wm) : M;
    float sc = EXP2(M - Mn);                 // 1.0 when !resc
#pragma unroll
    for (int r = 0; r < 16; ++r) s[r] = EXP2(s[r] - Mn);
    float q0 = (s[0] + s[1]) + (s[2] + s[3]);
    float q1 = (s[4] + s[5]) + (s[6] + s[7]);
    float q2 = (s[8] + s[9]) + (s[10] + s[11]);
    float q3 = (s[12] + s[13]) + (s[14] + s[15]);
    float ps = (q0 + q1) + (q2 + q3);
    if (commit) { L = L * sc + ps; M = Mn; }
    unsigned int c0 = CVTPK(s[0], s[1]),   c1 = CVTPK(s[2], s[3]);
    unsigned int c2 = CVTPK(s[4], s[5]),   c3 = CVTPK(s[6], s[7]);
    unsigned int c4 = CVTPK(s[8], s[9]),   c5 = CVTPK(s[10], s[11]);
    unsigned int c6 = CVTPK(s[12], s[13]), c7 = CVTPK(s[14], s[15]);
    LSWAP(c0, c2); LSWAP(c1, c3); LSWAP(c4, c6); LSWAP(c5, c7);
    P0[nxt].u[0] = c0; P0[nxt].u[1] = c1; P0[nxt].u[2] = c2; P0[nxt].u[3] = c3;
    P1[nxt].u[0] = c4; P1[nxt].u[1] = c5; P1[nxt].u[2] = c6; P1[nxt].u[3] = c7;

    // PV(t) with vf[cur], P*[cur] (o still in M(t) scale)
#pragma unroll
    for (int ct = 0; ct < 4; ++ct) {
      o[ct] = __builtin_amdgcn_mfma_f32_32x32x16_bf16(vf[cur][2 * ct],
                                                      P0[cur].v, o[ct], 0, 0, 0);
      o[ct] = __builtin_amdgcn_mfma_f32_32x32x16_bf16(vf[cur][2 * ct + 1],
                                                      P1[cur].v, o[ct], 0, 0, 0);
    }
    // deferred rescale to M(t+1) scale
    if (resc) {
#pragma unroll
      for (int ct = 0; ct < 4; ++ct)
#pragma unroll
        for (int r = 0; r < 16; ++r) o[ct][r] *= sc;
    }
  }

  // ---- merge the two m-halves ----
  L += __shfl_xor(L, 32);
  if (lane < 32) { sML[mh][0][lane] = M; sML[mh][1][lane] = L; }
  __syncthreads();
  float M0 = sML[0][0][ln], L0 = sML[0][1][ln];
  float M1 = sML[1][0][ln], L1 = sML[1][1][ln];
  float Ms = fmaxf(M0, M1);
  float a0 = EXP2(M0 - Ms), a1 = EXP2(M1 - Ms);
  float inv = 1.f / (L0 * a0 + L1 * a1);
  if (mh) {
#pragma unroll
    for (int ct = 0; ct < 4; ++ct)
#pragma unroll
      for (int r = 0; r < 16; ++r) {
        int cl = ct * 32 + (r & 3) + 8 * (r >> 2) + 4 * h;
        Ob[ch][cl][ln] = o[ct][r] * a1;
      }
  }
  __syncthreads();
  if (!mh) {
#pragma unroll
    for (int ct = 0; ct < 4; ++ct)
#pragma unroll
      for (int r = 0; r < 16; ++r) {
        int cl = ct * 32 + (r & 3) + 8 * (r >> 2) + 4 * h;
        size_t idx = ((size_t)b * C_ + ch * 128 + cl) * N_ + n0 + ln;
        out[idx] = (o[ct][r] * a0 + Ob[ch][cl][ln]) * inv + x[idx];
      }
  }
}

extern "C" void kernel_launch(void* const* d_in, const int* in_sizes, int n_in,
                              void* d_out, int out_size, void* d_ws, size_t ws_size,
                              hipStream_t stream) {
  const float* x  = (const float*)d_in[0];
  const float* wq = (const float*)d_in[1];
  const float* bq = (const float*)d_in[2];
  const float* wk = (const float*)d_in[3];
  const float* bk = (const float*)d_in[4];
  const float* wv = (const float*)d_in[5];
  const float* bv = (const float*)d_in[6];
  float* out = (float*)d_out;

  bf16* xT = (bf16*)d_ws;
  bf16* Qt = xT + (size_t)B_ * N_ * C_;
  bf16* Kt = Qt + (size_t)B_ * N_ * C8_;
  bf16* Vt = Kt + (size_t)B_ * N_ * C8_;
  bf16* Wb = Vt + (size_t)B_ * N_ * C_;

  k_convw<<<dim3(80), dim3(256), 0, stream>>>(wq, wk, wv, Wb);
  k_transpose<<<dim3(2048), dim3(256), 0, stream>>>(x, xT);
  k_proj_qk<<<dim3(256, 2), dim3(256), 0, stream>>>(xT, Wb, bq, bk, Qt, Kt);
  k_proj_v<<<dim3(2048), dim3(256), 0, stream>>>(xT, Wb, bv, Vt);
  k_attn<<<dim3(1024), dim3(256), 0, stream>>>(Qt, Kt, Vt, x, out);
}